// Round 1
// baseline (2577.144 us; speedup 1.0000x reference)
//
#include <hip/hip_runtime.h>
#include <cstddef>

#define BB 32
#define IC 2048
#define JD 16
#define NC 64
#define DD 32
#define ICHUNK 8
#define NBLK (IC / ICHUNK)   // 256 blocks, 1 per CU

// ---------------------------------------------------------------- zero s ----
__global__ void caps_zero(float* __restrict__ s) {
  int t = blockIdx.x * 256 + threadIdx.x;   // grid 256 x 256 = 65536
  s[t] = 0.0f;
}

// ------------------------------------------------------------- pass kernel --
// grid = 256 (i-chunks of 8), block = 512 (8 waves).
// lane l = n (0..63); wave w -> d in {4w..4w+3}. W fragment (64 f32) lives in
// registers and is reused for all 32 b -> W read exactly once per pass.
__global__ __launch_bounds__(512, 2) void caps_pass(
    const float* __restrict__ x, const float* __restrict__ W,
    const float* __restrict__ Vt, float* __restrict__ sOut,
    float* __restrict__ sPart, int r, int usePart)
{
  const int t  = threadIdx.x;
  const int w  = t >> 6;       // 0..7
  const int l  = t & 63;       // n
  const int d0 = w << 2;
  const int i0 = blockIdx.x * ICHUNK;

  __shared__ float part[2][8][64];   // cross-wave logit partials, dbuf

  float acc[BB][4];                  // s[b, n=l, d0..d0+3] partial over i-chunk
#pragma unroll
  for (int b = 0; b < BB; ++b)
#pragma unroll
    for (int k = 0; k < 4; ++k) acc[b][k] = 0.0f;

  for (int ii = 0; ii < ICHUNK; ++ii) {
    const int i = i0 + ii;
    // W[n=l, i, d0+k, j] : 4 rows x 16 j = 64 f32, contiguous 256B per lane
    const float4* Wp = reinterpret_cast<const float4*>(
        W + (((size_t)l * IC + i) * DD + d0) * JD);
    float4 wr[16];
#pragma unroll
    for (int q = 0; q < 16; ++q) wr[q] = Wp[q];

    if (r == 0) {
      // c = 1/64 exactly (softmax of zeros) -> no logits, no barriers
#pragma unroll
      for (int b = 0; b < BB; ++b) {
        const float* xp = x + ((size_t)b * IC + i) * JD;  // uniform -> s_load
        float u[4];
#pragma unroll
        for (int k = 0; k < 4; ++k) {
          float a = 0.f;
#pragma unroll
          for (int q = 0; q < 4; ++q) {
            float4 wv = wr[k * 4 + q];
            a += wv.x * xp[4*q] + wv.y * xp[4*q+1] + wv.z * xp[4*q+2] + wv.w * xp[4*q+3];
          }
          u[k] = a;
        }
#pragma unroll
        for (int k = 0; k < 4; ++k) acc[b][k] += 0.015625f * u[k];
      }
    } else {
#pragma unroll
      for (int b = 0; b < BB; ++b) {
        const float* xp = x + ((size_t)b * IC + i) * JD;
        float u[4];
#pragma unroll
        for (int k = 0; k < 4; ++k) {
          float a = 0.f;
#pragma unroll
          for (int q = 0; q < 4; ++q) {
            float4 wv = wr[k * 4 + q];
            a += wv.x * xp[4*q] + wv.y * xp[4*q+1] + wv.z * xp[4*q+2] + wv.w * xp[4*q+3];
          }
          u[k] = a;
        }
        // logit partial over this wave's 4 d's; Vt is [b][d][n] (lane-coalesced)
        const float* vp = Vt + ((size_t)b * DD + d0) * NC + l;
        float lp = u[0]*vp[0] + u[1]*vp[64] + u[2]*vp[128] + u[3]*vp[192];
        const int buf = b & 1;
        part[buf][w][l] = lp;
        __syncthreads();
        float logit = 0.f;
#pragma unroll
        for (int p = 0; p < 8; ++p) logit += part[buf][p][l];
        // softmax over n = 64 lanes. |logit| <~ 3 here, exp safe w/o max-sub
        // (mathematically identical to the reference's max-subtracted form).
        float e  = __expf(logit);
        float sm = e;
#pragma unroll
        for (int off = 32; off; off >>= 1) sm += __shfl_xor(sm, off);
        float c = e / sm;
#pragma unroll
        for (int k = 0; k < 4; ++k) acc[b][k] += c * u[k];
      }
    }
  }

  if (usePart) {
    // partials layout float4[blk][b][w][l] -> lane-consecutive 16B stores
#pragma unroll
    for (int b = 0; b < BB; ++b) {
      float4 v = make_float4(acc[b][0], acc[b][1], acc[b][2], acc[b][3]);
      size_t off = (((size_t)blockIdx.x * BB + b) * 8 + w) * 64 + l;
      reinterpret_cast<float4*>(sPart)[off] = v;
    }
  } else {
#pragma unroll
    for (int b = 0; b < BB; ++b) {
      float* sp = sOut + ((size_t)b * NC + l) * DD + d0;
#pragma unroll
      for (int k = 0; k < 4; ++k) atomicAdd(sp + k, acc[b][k]);
    }
  }
}

// ----------------------------------------------------------- tree reduce ----
// sum 256 block-partials -> s[b][n][d]. grid 64 x 256 = 16384 threads (float4)
__global__ void caps_reduce(const float4* __restrict__ sPart, float* __restrict__ s) {
  int q = blockIdx.x * 256 + threadIdx.x;    // 0..16383 = b*512 + w*64 + l
  int b = q >> 9, rem = q & 511, w = rem >> 6, l = rem & 63;
  float4 sum = make_float4(0.f, 0.f, 0.f, 0.f);
#pragma unroll 8
  for (int p = 0; p < NBLK; ++p) {
    float4 v = sPart[(size_t)p * 16384 + q];
    sum.x += v.x; sum.y += v.y; sum.z += v.z; sum.w += v.w;
  }
  *reinterpret_cast<float4*>(s + ((size_t)b * NC + l) * DD + (w << 2)) = sum;
}

// ---------------------------------------------------------------- squash ----
// one (b,n) per 32-lane half-wave. mode 0: Vt = v; 1: Vt += v; 2: out = v.
__global__ void caps_squash(float* __restrict__ s, float* __restrict__ Vt,
                            float* __restrict__ out, int mode)
{
  const int t = threadIdx.x;
  const int g = blockIdx.x * 8 + (t >> 5);   // b*64+n, grid 256
  const int d = t & 31;
  const int b = g >> 6;
  const int n = g & 63;
  float v  = s[(size_t)g * DD + d];
  float s2 = v * v;
#pragma unroll
  for (int off = 16; off; off >>= 1) s2 += __shfl_xor(s2, off);  // over 32 d's
  float scale = s2 / ((1.0f + s2) * sqrtf(s2 + 1e-7f));
  float vd = scale * v;
  if (mode == 2) {
    out[(size_t)g * DD + d] = vd;
  } else {
    float* vt = Vt + ((size_t)b * DD + d) * NC + n;   // transposed [b][d][n]
    if (mode == 0) *vt = vd; else *vt += vd;
    s[(size_t)g * DD + d] = 0.0f;   // re-zero for next pass (atomic path)
  }
}

// ---------------------------------------------------------------------------
extern "C" void kernel_launch(void* const* d_in, const int* in_sizes, int n_in,
                              void* d_out, int out_size, void* d_ws, size_t ws_size,
                              hipStream_t stream) {
  const float* x = (const float*)d_in[0];
  const float* W = (const float*)d_in[1];
  float* out   = (float*)d_out;
  float* s     = (float*)d_ws;           // 64K f32
  float* Vt    = s + 65536;              // 64K f32, layout [b][d][n]
  float* sPart = Vt + 65536;             // 256 * 64K f32 = 64 MB
  const size_t need = (2ull * 65536 + (size_t)NBLK * 65536) * sizeof(float);
  const int usePart = (ws_size >= need) ? 1 : 0;

  caps_zero<<<256, 256, 0, stream>>>(s);
  for (int r = 0; r < 3; ++r) {
    caps_pass<<<NBLK, 512, 0, stream>>>(x, W, Vt, s, sPart, r, usePart);
    if (usePart) caps_reduce<<<64, 256, 0, stream>>>((const float4*)sPart, s);
    caps_squash<<<256, 256, 0, stream>>>(s, Vt, out, r == 2 ? 2 : (r == 0 ? 0 : 1));
  }
}

// Round 2
// 1696.754 us; speedup vs baseline: 1.5189x; 1.5189x over previous
//
#include <hip/hip_runtime.h>
#include <cstddef>

#define BB 32
#define IC 2048
#define JD 16
#define NC 64
#define DD 32
#define ICHUNK 8
#define NBLK (IC / ICHUNK)   // 256 blocks, 1 per CU

// ---------------------------------------------------------------- helpers ---
template<int CTRL>
__device__ __forceinline__ float dpp_mov_f(float v) {
  // DPP row ops operate within 16-lane rows; bound_ctrl=true (all lanes valid
  // for row_ror with full exec).
  int x = __builtin_amdgcn_mov_dpp(__float_as_int(v), CTRL, 0xf, 0xf, true);
  return __int_as_float(x);
}
// sum over the 16 lanes of each row (rotate-reduce, VALU pipe, no LDS)
__device__ __forceinline__ float row16_sum(float v) {
  v += dpp_mov_f<0x121>(v);  // row_ror:1
  v += dpp_mov_f<0x122>(v);  // row_ror:2
  v += dpp_mov_f<0x124>(v);  // row_ror:4
  v += dpp_mov_f<0x128>(v);  // row_ror:8
  return v;
}

// ---------------------------------------------------------------- zero s ----
__global__ void caps_zero(float* __restrict__ s) {
  int t = blockIdx.x * 256 + threadIdx.x;   // grid 256 x 256 = 65536
  s[t] = 0.0f;
}

// ------------------------------------------------------------- pass kernel --
// grid = 256 (i-chunks of 8), block = 1024 (16 waves, 50% occupancy).
// wave w owns n in {4w..4w+3}; lane l: row = l>>4 -> n_local, dg = l&15 ->
// d in {2dg, 2dg+1}. W fragment (32 f32) in regs, reused across all 32 b.
// acc = 32 b x 2 d = 64 VGPRs. Target: 128 VGPRs, zero scratch.
__global__ __launch_bounds__(1024, 4) void caps_pass(
    const float* __restrict__ x, const float* __restrict__ W,
    const float* __restrict__ V, float* __restrict__ sOut,
    float* __restrict__ sPart, int r, int usePart)
{
  const int t   = threadIdx.x;
  const int w   = t >> 6;           // 0..15
  const int l   = t & 63;
  const int n   = (w << 2) | (l >> 4);
  const int d0  = (l & 15) << 1;    // 2 d's per thread
  const int i0  = blockIdx.x * ICHUNK;

  __shared__ float den[2][4];       // softmax denominators, double-buffered

  float acc0[BB], acc1[BB];
#pragma unroll
  for (int b = 0; b < BB; ++b) { acc0[b] = 0.0f; acc1[b] = 0.0f; }

  int buf = 0;
  for (int ii = 0; ii < ICHUNK; ++ii) {
    const int i = i0 + ii;
    // W[n, i, d0..d0+1, 0..15] : 32 f32 = 128 B contiguous per thread
    const float4* Wp = reinterpret_cast<const float4*>(
        W + (((size_t)n * IC + i) * DD + d0) * JD);
    float4 wr[8];
#pragma unroll
    for (int q = 0; q < 8; ++q) wr[q] = Wp[q];

    if (r == 0) {
      // c = 1/64 exactly (softmax of zeros): no logits, no barriers
#pragma unroll
      for (int b = 0; b < BB; ++b) {
        const float* xp = x + ((size_t)b * IC + i) * JD;   // uniform -> s_load
        float u0 = 0.f, u1 = 0.f;
#pragma unroll
        for (int q = 0; q < 4; ++q) {
          float4 w0 = wr[q], w1 = wr[4 + q];
          float x0 = xp[4*q], x1 = xp[4*q+1], x2 = xp[4*q+2], x3 = xp[4*q+3];
          u0 += w0.x*x0 + w0.y*x1 + w0.z*x2 + w0.w*x3;
          u1 += w1.x*x0 + w1.y*x1 + w1.z*x2 + w1.w*x3;
        }
        acc0[b] += u0 * 0.015625f;
        acc1[b] += u1 * 0.015625f;
      }
    } else {
#pragma unroll
      for (int bq = 0; bq < 8; ++bq) {          // quads of 4 b
        if (t < 4) den[buf][t] = 0.0f;
        __syncthreads();                         // zero visible before atomics
        float u0a[4], u1a[4], ea[4];
#pragma unroll
        for (int bb = 0; bb < 4; ++bb) {
          const int b = bq * 4 + bb;
          const float* xp = x + ((size_t)b * IC + i) * JD;
          float u0 = 0.f, u1 = 0.f;
#pragma unroll
          for (int q = 0; q < 4; ++q) {
            float4 w0 = wr[q], w1 = wr[4 + q];
            float x0 = xp[4*q], x1 = xp[4*q+1], x2 = xp[4*q+2], x3 = xp[4*q+3];
            u0 += w0.x*x0 + w0.y*x1 + w0.z*x2 + w0.w*x3;
            u1 += w1.x*x0 + w1.y*x1 + w1.z*x2 + w1.w*x3;
          }
          // logit partial for this thread's 2 d's, then 16-lane row reduce
          const float2 vv = *reinterpret_cast<const float2*>(
              V + ((size_t)b * NC + n) * DD + d0);
          float lp = u0 * vv.x + u1 * vv.y;
          float logit = row16_sum(lp);           // all 16 lanes of row have it
          // |logit| small (V squashed, |u|~0.8): exp safe without max-sub;
          // mathematically identical to reference's max-subtracted softmax.
          float e = __expf(logit);
          u0a[bb] = u0; u1a[bb] = u1; ea[bb] = e;
          // denominator: sum e over this wave's 4 rows, then across 16 waves
          float es = e + __shfl_xor(e, 16);      // pair rows within 32-half
          if ((l & 31) == 0) atomicAdd(&den[buf][bb], es);
        }
        __syncthreads();                         // den complete
#pragma unroll
        for (int bb = 0; bb < 4; ++bb) {
          const int b = bq * 4 + bb;
          float c = ea[bb] / den[buf][bb];       // broadcast LDS read
          acc0[b] += c * u0a[bb];
          acc1[b] += c * u1a[bb];
        }
        buf ^= 1;
      }
    }
  }

  if (usePart) {
    // sPart layout [blk][b][n][d] f32 -> float2 stores, coalesced per row
#pragma unroll
    for (int b = 0; b < BB; ++b) {
      float2 v2 = make_float2(acc0[b], acc1[b]);
      size_t off = ((size_t)blockIdx.x * BB + b) * 2048 + (size_t)n * DD + d0;
      *reinterpret_cast<float2*>(sPart + off) = v2;
    }
  } else {
#pragma unroll
    for (int b = 0; b < BB; ++b) {
      float* sp = sOut + ((size_t)b * NC + n) * DD + d0;
      atomicAdd(sp, acc0[b]);
      atomicAdd(sp + 1, acc1[b]);
    }
  }
}

// ------------------------------------------------------- tree reduce L1/L2 --
// q indexes float4 over [b][n][d] = 16384 float4.
// L1: grid 512 = (64 q-blocks) x (8 p-groups of 32 partials each)
__global__ void caps_reduce1(const float4* __restrict__ sPart,
                             float4* __restrict__ part2) {
  int pg = blockIdx.x & 7, qb = blockIdx.x >> 3;
  int q = qb * 256 + threadIdx.x;
  float4 sum = make_float4(0.f, 0.f, 0.f, 0.f);
#pragma unroll 8
  for (int p = 0; p < 32; ++p) {
    float4 v = sPart[(size_t)(pg * 32 + p) * 16384 + q];
    sum.x += v.x; sum.y += v.y; sum.z += v.z; sum.w += v.w;
  }
  part2[(size_t)pg * 16384 + q] = sum;
}
// L2: grid 64 x 256 -> s
__global__ void caps_reduce2(const float4* __restrict__ part2,
                             float4* __restrict__ s) {
  int q = blockIdx.x * 256 + threadIdx.x;
  float4 sum = make_float4(0.f, 0.f, 0.f, 0.f);
#pragma unroll
  for (int p = 0; p < 8; ++p) {
    float4 v = part2[(size_t)p * 16384 + q];
    sum.x += v.x; sum.y += v.y; sum.z += v.z; sum.w += v.w;
  }
  s[q] = sum;
}
// single-level fallback (ws too small for part2): grid 64 x 256
__global__ void caps_reduceS(const float4* __restrict__ sPart,
                             float4* __restrict__ s) {
  int q = blockIdx.x * 256 + threadIdx.x;
  float4 sum = make_float4(0.f, 0.f, 0.f, 0.f);
#pragma unroll 8
  for (int p = 0; p < NBLK; ++p) {
    float4 v = sPart[(size_t)p * 16384 + q];
    sum.x += v.x; sum.y += v.y; sum.z += v.z; sum.w += v.w;
  }
  s[q] = sum;
}

// ---------------------------------------------------------------- squash ----
// one (b,n) per 32-lane half-wave; V layout [b][n][d] (same as s).
__global__ void caps_squash(const float* __restrict__ s, float* __restrict__ V,
                            float* __restrict__ out, int mode)
{
  const int t = threadIdx.x;
  const int g = blockIdx.x * 8 + (t >> 5);   // b*64+n, grid 256
  const int d = t & 31;
  float v  = s[(size_t)g * DD + d];
  float s2 = v * v;
#pragma unroll
  for (int off = 16; off; off >>= 1) s2 += __shfl_xor(s2, off);  // 32 d's
  float scale = s2 / ((1.0f + s2) * sqrtf(s2 + 1e-7f));
  float vd = scale * v;
  if (mode == 2)      out[(size_t)g * DD + d] = vd;
  else if (mode == 0) V[(size_t)g * DD + d] = vd;
  else                V[(size_t)g * DD + d] += vd;
}

// ---------------------------------------------------------------------------
extern "C" void kernel_launch(void* const* d_in, const int* in_sizes, int n_in,
                              void* d_out, int out_size, void* d_ws, size_t ws_size,
                              hipStream_t stream) {
  const float* x = (const float*)d_in[0];
  const float* W = (const float*)d_in[1];
  float* out   = (float*)d_out;
  float* s     = (float*)d_ws;                       // 64K f32
  float* V     = s + 65536;                          // 64K f32 [b][n][d]
  float* sPart = V + 65536;                          // 256*64K f32 = 64 MB
  float* part2 = sPart + (size_t)NBLK * 65536;       // 512K f32 = 2 MB

  const size_t need1 = (2ull * 65536 + (size_t)NBLK * 65536) * 4;
  const size_t need2 = need1 + 8ull * 16384 * 16;
  const int usePart  = (ws_size >= need1) ? 1 : 0;
  const int useTwo   = (ws_size >= need2) ? 1 : 0;

  for (int r = 0; r < 3; ++r) {
    if (!usePart) caps_zero<<<256, 256, 0, stream>>>(s);
    caps_pass<<<NBLK, 1024, 0, stream>>>(x, W, V, s, sPart, r, usePart);
    if (usePart) {
      if (useTwo) {
        caps_reduce1<<<512, 256, 0, stream>>>((const float4*)sPart, (float4*)part2);
        caps_reduce2<<<64, 256, 0, stream>>>((const float4*)part2, (float4*)s);
      } else {
        caps_reduceS<<<64, 256, 0, stream>>>((const float4*)sPart, (float4*)s);
      }
    }
    caps_squash<<<256, 256, 0, stream>>>(s, V, out, r == 2 ? 2 : (r == 0 ? 0 : 1));
  }
}

// Round 3
// 1609.050 us; speedup vs baseline: 1.6017x; 1.0545x over previous
//
#include <hip/hip_runtime.h>
#include <cstddef>

#define BB 32
#define IC 2048
#define JD 16
#define NC 64
#define DD 32
#define ICHUNK 8
#define NBLK (IC / ICHUNK)   // 256 blocks, 1 per CU

// ---------------------------------------------------------------- helpers ---
template<int CTRL>
__device__ __forceinline__ float dpp_mov_f(float v) {
  int x = __builtin_amdgcn_mov_dpp(__float_as_int(v), CTRL, 0xf, 0xf, true);
  return __int_as_float(x);
}
// sum over the 16 lanes of each row (rotate-reduce, VALU pipe, no LDS)
__device__ __forceinline__ float row16_sum(float v) {
  v += dpp_mov_f<0x121>(v);  // row_ror:1
  v += dpp_mov_f<0x122>(v);  // row_ror:2
  v += dpp_mov_f<0x124>(v);  // row_ror:4
  v += dpp_mov_f<0x128>(v);  // row_ror:8
  return v;
}

// ---------------------------------------------------------------- zero s ----
__global__ void caps_zero(float* __restrict__ s) {
  int t = blockIdx.x * 256 + threadIdx.x;
  s[t] = 0.0f;
}

// ------------------------------------------------------------- pass kernel --
// grid = 256 (i-chunks of 8), block = 1024 (16 waves).
// wave w owns n in {4w..4w+3}; lane l: row = l>>4 -> n_local, dg = l&15 ->
// d in {2dg, 2dg+1}. W fragment (32 f32) in regs, reused across all 32 b.
// acc = 64 VGPRs + wr 32 + temps ~28 -> ~124 live. waves_per_eu(4,4) pins the
// allocator at 4 waves/EU (128 VGPR budget) so it does NOT clamp to 64+spill
// (R2: VGPR_Count=64, 1.6 GB of scratch traffic).
__global__ __launch_bounds__(1024) __attribute__((amdgpu_waves_per_eu(4, 4)))
void caps_pass(
    const float* __restrict__ x, const float* __restrict__ W,
    const float* __restrict__ V, float* __restrict__ sOut,
    float* __restrict__ sPart, int r, int usePart)
{
  const int t   = threadIdx.x;
  const int w   = t >> 6;           // 0..15
  const int l   = t & 63;
  const int n   = (w << 2) | (l >> 4);
  const int d0  = (l & 15) << 1;    // 2 d's per thread
  const int i0  = blockIdx.x * ICHUNK;

  __shared__ float den[2][8][4];    // softmax denominators, ii-parity dbuf

  float acc0[BB], acc1[BB];
#pragma unroll
  for (int b = 0; b < BB; ++b) { acc0[b] = 0.0f; acc1[b] = 0.0f; }

  for (int ii = 0; ii < ICHUNK; ++ii) {
    const int i = i0 + ii;
    const int p = ii & 1;
    // W[n, i, d0..d0+1, 0..15] : 32 f32 = 128 B contiguous per thread
    const float4* Wp = reinterpret_cast<const float4*>(
        W + (((size_t)n * IC + i) * DD + d0) * JD);
    float4 wr[8];
#pragma unroll
    for (int q = 0; q < 8; ++q) wr[q] = Wp[q];

    if (r == 0) {
      // c = 1/64 exactly (softmax of zeros): no logits, no barriers
#pragma unroll
      for (int b = 0; b < BB; ++b) {
        const float* xp = x + ((size_t)b * IC + i) * JD;   // uniform -> s_load
        float u0 = 0.f, u1 = 0.f;
#pragma unroll
        for (int q = 0; q < 4; ++q) {
          float4 w0 = wr[q], w1 = wr[4 + q];
          float x0 = xp[4*q], x1 = xp[4*q+1], x2 = xp[4*q+2], x3 = xp[4*q+3];
          u0 += w0.x*x0 + w0.y*x1 + w0.z*x2 + w0.w*x3;
          u1 += w1.x*x0 + w1.y*x1 + w1.z*x2 + w1.w*x3;
        }
        acc0[b] += u0 * 0.015625f;
        acc1[b] += u1 * 0.015625f;
      }
    } else {
      if (t < 32) ((float*)den[p])[t] = 0.0f;   // zero all 8 quad-slots
      __syncthreads();
#pragma unroll
      for (int bq = 0; bq < 8; ++bq) {          // quads of 4 b
        float u0a[4], u1a[4], ea[4];
#pragma unroll
        for (int bb = 0; bb < 4; ++bb) {
          const int b = bq * 4 + bb;
          const float* xp = x + ((size_t)b * IC + i) * JD;
          float u0 = 0.f, u1 = 0.f;
#pragma unroll
          for (int q = 0; q < 4; ++q) {
            float4 w0 = wr[q], w1 = wr[4 + q];
            float x0 = xp[4*q], x1 = xp[4*q+1], x2 = xp[4*q+2], x3 = xp[4*q+3];
            u0 += w0.x*x0 + w0.y*x1 + w0.z*x2 + w0.w*x3;
            u1 += w1.x*x0 + w1.y*x1 + w1.z*x2 + w1.w*x3;
          }
          // logit partial for this thread's 2 d's, then 16-lane row reduce
          const float2 vv = *reinterpret_cast<const float2*>(
              V + ((size_t)b * NC + n) * DD + d0);
          float lp = u0 * vv.x + u1 * vv.y;
          float logit = row16_sum(lp);           // uniform within 16-lane row
          // |logit| small (V squashed): exp safe without max-sub;
          // identical to reference's max-subtracted softmax.
          float e = __expf(logit);
          u0a[bb] = u0; u1a[bb] = u1; ea[bb] = e;
          float es = e + __shfl_xor(e, 16);      // rows 0+1 / 2+3 pair-sum
          if ((l & 31) == 0) atomicAdd(&den[p][bq][bb], es);
        }
        __syncthreads();                         // den[p][bq] complete
#pragma unroll
        for (int bb = 0; bb < 4; ++bb) {
          const int b = bq * 4 + bb;
          float c = ea[bb] / den[p][bq][bb];     // broadcast LDS read
          acc0[b] += c * u0a[bb];
          acc1[b] += c * u1a[bb];
        }
        // next quad's atomics hit a different slot; next ii uses other parity
        // -> no trailing barrier, no cross-ii race.
      }
    }
  }

  if (usePart) {
    // sPart layout [blk][b][n][d] f32 -> float2 stores, coalesced per row
#pragma unroll
    for (int b = 0; b < BB; ++b) {
      float2 v2 = make_float2(acc0[b], acc1[b]);
      size_t off = ((size_t)blockIdx.x * BB + b) * 2048 + (size_t)n * DD + d0;
      *reinterpret_cast<float2*>(sPart + off) = v2;
    }
  } else {
#pragma unroll
    for (int b = 0; b < BB; ++b) {
      float* sp = sOut + ((size_t)b * NC + n) * DD + d0;
      atomicAdd(sp, acc0[b]);
      atomicAdd(sp + 1, acc1[b]);
    }
  }
}

// ------------------------------------------------------- tree reduce L1/L2 --
// q indexes float4 over [b][n][d] = 16384 float4.
__global__ void caps_reduce1(const float4* __restrict__ sPart,
                             float4* __restrict__ part2) {
  int pg = blockIdx.x & 7, qb = blockIdx.x >> 3;
  int q = qb * 256 + threadIdx.x;
  float4 sum = make_float4(0.f, 0.f, 0.f, 0.f);
#pragma unroll 8
  for (int p = 0; p < 32; ++p) {
    float4 v = sPart[(size_t)(pg * 32 + p) * 16384 + q];
    sum.x += v.x; sum.y += v.y; sum.z += v.z; sum.w += v.w;
  }
  part2[(size_t)pg * 16384 + q] = sum;
}
__global__ void caps_reduce2(const float4* __restrict__ part2,
                             float4* __restrict__ s) {
  int q = blockIdx.x * 256 + threadIdx.x;
  float4 sum = make_float4(0.f, 0.f, 0.f, 0.f);
#pragma unroll
  for (int p = 0; p < 8; ++p) {
    float4 v = part2[(size_t)p * 16384 + q];
    sum.x += v.x; sum.y += v.y; sum.z += v.z; sum.w += v.w;
  }
  s[q] = sum;
}
__global__ void caps_reduceS(const float4* __restrict__ sPart,
                             float4* __restrict__ s) {
  int q = blockIdx.x * 256 + threadIdx.x;
  float4 sum = make_float4(0.f, 0.f, 0.f, 0.f);
#pragma unroll 8
  for (int p = 0; p < NBLK; ++p) {
    float4 v = sPart[(size_t)p * 16384 + q];
    sum.x += v.x; sum.y += v.y; sum.z += v.z; sum.w += v.w;
  }
  s[q] = sum;
}

// ---------------------------------------------------------------- squash ----
// one (b,n) per 32-lane half-wave; V layout [b][n][d] (same as s).
__global__ void caps_squash(const float* __restrict__ s, float* __restrict__ V,
                            float* __restrict__ out, int mode)
{
  const int t = threadIdx.x;
  const int g = blockIdx.x * 8 + (t >> 5);   // b*64+n, grid 256
  const int d = t & 31;
  float v  = s[(size_t)g * DD + d];
  float s2 = v * v;
#pragma unroll
  for (int off = 16; off; off >>= 1) s2 += __shfl_xor(s2, off);  // 32 d's
  float scale = s2 / ((1.0f + s2) * sqrtf(s2 + 1e-7f));
  float vd = scale * v;
  if (mode == 2)      out[(size_t)g * DD + d] = vd;
  else if (mode == 0) V[(size_t)g * DD + d] = vd;
  else                V[(size_t)g * DD + d] += vd;
}

// ---------------------------------------------------------------------------
extern "C" void kernel_launch(void* const* d_in, const int* in_sizes, int n_in,
                              void* d_out, int out_size, void* d_ws, size_t ws_size,
                              hipStream_t stream) {
  const float* x = (const float*)d_in[0];
  const float* W = (const float*)d_in[1];
  float* out   = (float*)d_out;
  float* s     = (float*)d_ws;                       // 64K f32
  float* V     = s + 65536;                          // 64K f32 [b][n][d]
  float* sPart = V + 65536;                          // 256*64K f32 = 64 MB
  float* part2 = sPart + (size_t)NBLK * 65536;       // 512K f32 = 2 MB

  const size_t need1 = (2ull * 65536 + (size_t)NBLK * 65536) * 4;
  const size_t need2 = need1 + 8ull * 16384 * 16;
  const int usePart  = (ws_size >= need1) ? 1 : 0;
  const int useTwo   = (ws_size >= need2) ? 1 : 0;

  for (int r = 0; r < 3; ++r) {
    if (!usePart) caps_zero<<<256, 256, 0, stream>>>(s);
    caps_pass<<<NBLK, 1024, 0, stream>>>(x, W, V, s, sPart, r, usePart);
    if (usePart) {
      if (useTwo) {
        caps_reduce1<<<512, 256, 0, stream>>>((const float4*)sPart, (float4*)part2);
        caps_reduce2<<<64, 256, 0, stream>>>((const float4*)part2, (float4*)s);
      } else {
        caps_reduceS<<<64, 256, 0, stream>>>((const float4*)sPart, (float4*)s);
      }
    }
    caps_squash<<<256, 256, 0, stream>>>(s, V, out, r == 2 ? 2 : (r == 0 ? 0 : 1));
  }
}

// Round 4
// 889.327 us; speedup vs baseline: 2.8979x; 1.8093x over previous
//
#include <hip/hip_runtime.h>
#include <cstddef>

#define BB 32
#define BH 16                 // b per block (half of BB)
#define IC 2048
#define JD 16
#define NC 64
#define DD 32
#define ICHUNK 16
#define NIC (IC / ICHUNK)     // 128 i-chunks; grid = 128 x 2 b-halves = 256

// ---------------------------------------------------------------- helpers ---
template<int CTRL>
__device__ __forceinline__ float dpp_mov_f(float v) {
  int x = __builtin_amdgcn_mov_dpp(__float_as_int(v), CTRL, 0xf, 0xf, true);
  return __int_as_float(x);
}
// sum over the 16 lanes of each row (rotate-reduce, VALU pipe, no LDS)
__device__ __forceinline__ float row16_sum(float v) {
  v += dpp_mov_f<0x121>(v);  // row_ror:1
  v += dpp_mov_f<0x122>(v);  // row_ror:2
  v += dpp_mov_f<0x124>(v);  // row_ror:4
  v += dpp_mov_f<0x128>(v);  // row_ror:8
  return v;
}

// ---------------------------------------------------------------- zero s ----
__global__ void caps_zero(float* __restrict__ s) {
  int t = blockIdx.x * 256 + threadIdx.x;
  s[t] = 0.0f;
}

// ------------------------------------------------------------- pass kernel --
// grid = 256: (128 i-chunks) x (2 b-halves). block = 1024 (16 waves, 1/CU).
// wave w owns n in {4w..4w+3}; lane l: n_loc = l>>4, dg = l&15 -> d {2dg,2dg+1}.
// acc = 16 b x 2 d = 32 VGPRs; W frag 32; live ~85 -> fits 128, mild spill at 64.
// XCD pairing: blk = xcd + 8*slot (dispatch round-robin); both b-halves of an
// i-chunk are consecutive slots on the SAME XCD -> 2nd W read hits its L2.
// Mapping is bijective -> correctness never depends on the physical XCD map.
__global__ __attribute__((amdgpu_flat_work_group_size(1024, 1024),
                          amdgpu_waves_per_eu(4, 4)))
void caps_pass(const float* __restrict__ x, const float* __restrict__ W,
               const float* __restrict__ V, float* __restrict__ sOut,
               float* __restrict__ sPart, int r, int usePart)
{
  const int t    = threadIdx.x;
  const int w    = t >> 6;           // 0..15
  const int l    = t & 63;
  const int n    = (w << 2) | (l >> 4);
  const int d0   = (l & 15) << 1;    // 2 d's per thread
  const int blk  = blockIdx.x;
  const int xcd  = blk & 7;
  const int slot = blk >> 3;         // 0..31
  const int ic   = xcd * 16 + (slot >> 1);   // 0..127
  const int bh   = slot & 1;
  const int i0   = ic * ICHUNK;
  const int bbase = bh * BH;

  __shared__ float den[2][4][4];     // [ii-parity][b-quad][bb]

  float acc0[BH], acc1[BH];
#pragma unroll
  for (int b = 0; b < BH; ++b) { acc0[b] = 0.0f; acc1[b] = 0.0f; }

  for (int ii = 0; ii < ICHUNK; ++ii) {
    const int i = i0 + ii;
    const int p = ii & 1;
    // W[n, i, d0..d0+1, 0..15] : 32 f32 = 128 B contiguous per thread
    const float4* Wp = reinterpret_cast<const float4*>(
        W + (((size_t)n * IC + i) * DD + d0) * JD);
    float4 wr[8];
#pragma unroll
    for (int q = 0; q < 8; ++q) wr[q] = Wp[q];

    if (r == 0) {
      // c = 1/64 exactly (softmax of zeros): no logits, no barriers
#pragma unroll
      for (int bl = 0; bl < BH; ++bl) {
        const int b = bbase + bl;
        const float* xp = x + ((size_t)b * IC + i) * JD;   // uniform -> s_load
        float u0 = 0.f, u1 = 0.f;
#pragma unroll
        for (int q = 0; q < 4; ++q) {
          float4 w0 = wr[q], w1 = wr[4 + q];
          float x0 = xp[4*q], x1 = xp[4*q+1], x2 = xp[4*q+2], x3 = xp[4*q+3];
          u0 += w0.x*x0 + w0.y*x1 + w0.z*x2 + w0.w*x3;
          u1 += w1.x*x0 + w1.y*x1 + w1.z*x2 + w1.w*x3;
        }
        acc0[bl] += u0 * 0.015625f;
        acc1[bl] += u1 * 0.015625f;
      }
    } else {
      if (t < 16) ((float*)den[p])[t] = 0.0f;   // zero all 4 quad-slots
      __syncthreads();
#pragma unroll
      for (int bq = 0; bq < 4; ++bq) {          // quads of 4 b
        float u0a[4], u1a[4], ea[4];
#pragma unroll
        for (int bb = 0; bb < 4; ++bb) {
          const int bl = bq * 4 + bb;
          const int b  = bbase + bl;
          const float* xp = x + ((size_t)b * IC + i) * JD;
          float u0 = 0.f, u1 = 0.f;
#pragma unroll
          for (int q = 0; q < 4; ++q) {
            float4 w0 = wr[q], w1 = wr[4 + q];
            float x0 = xp[4*q], x1 = xp[4*q+1], x2 = xp[4*q+2], x3 = xp[4*q+3];
            u0 += w0.x*x0 + w0.y*x1 + w0.z*x2 + w0.w*x3;
            u1 += w1.x*x0 + w1.y*x1 + w1.z*x2 + w1.w*x3;
          }
          const float2 vv = *reinterpret_cast<const float2*>(
              V + ((size_t)b * NC + n) * DD + d0);
          float lp = u0 * vv.x + u1 * vv.y;
          float logit = row16_sum(lp);           // uniform within 16-lane row
          // |logit| small (V squashed): exp safe w/o max-sub; identical to
          // the reference's max-subtracted softmax.
          float e = __expf(logit);
          u0a[bb] = u0; u1a[bb] = u1; ea[bb] = e;
          float es = e + __shfl_xor(e, 16);      // pair rows within 32-half
          if ((l & 31) == 0) atomicAdd(&den[p][bq][bb], es);
        }
        __syncthreads();                         // den[p][bq] complete
#pragma unroll
        for (int bb = 0; bb < 4; ++bb) {
          const int bl = bq * 4 + bb;
          float c = ea[bb] / den[p][bq][bb];     // broadcast LDS read
          acc0[bl] += c * u0a[bb];
          acc1[bl] += c * u1a[bb];
        }
      }
    }
  }

  if (usePart) {
    // sPart layout [bh][ic][bl][n][d] -> float2 stores, coalesced per row
#pragma unroll
    for (int bl = 0; bl < BH; ++bl) {
      float2 v2 = make_float2(acc0[bl], acc1[bl]);
      size_t off = ((((size_t)bh * NIC + ic) * BH + bl) * NC + n) * DD + d0;
      *reinterpret_cast<float2*>(sPart + off) = v2;
    }
  } else {
#pragma unroll
    for (int bl = 0; bl < BH; ++bl) {
      float* sp = sOut + ((size_t)(bbase + bl) * NC + n) * DD + d0;
      atomicAdd(sp, acc0[bl]);
      atomicAdd(sp + 1, acc1[bl]);
    }
  }
}

// ------------------------------------------------------- tree reduce L1/L2 --
// per half h: sPart_h = [NIC=128][8192 float4]; s_f4[h*8192+q] = sum over ic.
__global__ void caps_reduce1(const float4* __restrict__ sPart,
                             float4* __restrict__ part2) {
  int blk = blockIdx.x;              // 512 = 2h x 8pg x 32qb
  int h  = blk >> 8;
  int pg = (blk >> 5) & 7;
  int qb = blk & 31;
  int q  = qb * 256 + threadIdx.x;   // 0..8191
  const float4* base = sPart + (size_t)h * NIC * 8192;
  float4 sum = make_float4(0.f, 0.f, 0.f, 0.f);
#pragma unroll 8
  for (int p = 0; p < 16; ++p) {
    float4 v = base[(size_t)(pg * 16 + p) * 8192 + q];
    sum.x += v.x; sum.y += v.y; sum.z += v.z; sum.w += v.w;
  }
  part2[((size_t)h * 8 + pg) * 8192 + q] = sum;
}
__global__ void caps_reduce2(const float4* __restrict__ part2,
                             float4* __restrict__ s) {
  int blk = blockIdx.x;              // 64 = 2h x 32qb
  int h = blk >> 5, qb = blk & 31;
  int q = qb * 256 + threadIdx.x;
  float4 sum = make_float4(0.f, 0.f, 0.f, 0.f);
#pragma unroll
  for (int pg = 0; pg < 8; ++pg) {
    float4 v = part2[((size_t)h * 8 + pg) * 8192 + q];
    sum.x += v.x; sum.y += v.y; sum.z += v.z; sum.w += v.w;
  }
  s[(size_t)h * 8192 + q] = sum;
}
__global__ void caps_reduceS(const float4* __restrict__ sPart,
                             float4* __restrict__ s) {
  int blk = blockIdx.x;              // 64 = 2h x 32qb
  int h = blk >> 5, qb = blk & 31;
  int q = qb * 256 + threadIdx.x;
  const float4* base = sPart + (size_t)h * NIC * 8192;
  float4 sum = make_float4(0.f, 0.f, 0.f, 0.f);
#pragma unroll 8
  for (int p = 0; p < NIC; ++p) {
    float4 v = base[(size_t)p * 8192 + q];
    sum.x += v.x; sum.y += v.y; sum.z += v.z; sum.w += v.w;
  }
  s[(size_t)h * 8192 + q] = sum;
}

// ---------------------------------------------------------------- squash ----
// one (b,n) per 32-lane half-wave; V layout [b][n][d] (same as s).
__global__ void caps_squash(const float* __restrict__ s, float* __restrict__ V,
                            float* __restrict__ out, int mode)
{
  const int t = threadIdx.x;
  const int g = blockIdx.x * 8 + (t >> 5);   // b*64+n, grid 256
  const int d = t & 31;
  float v  = s[(size_t)g * DD + d];
  float s2 = v * v;
#pragma unroll
  for (int off = 16; off; off >>= 1) s2 += __shfl_xor(s2, off);  // 32 d's
  float scale = s2 / ((1.0f + s2) * sqrtf(s2 + 1e-7f));
  float vd = scale * v;
  if (mode == 2)      out[(size_t)g * DD + d] = vd;
  else if (mode == 0) V[(size_t)g * DD + d] = vd;
  else                V[(size_t)g * DD + d] += vd;
}

// ---------------------------------------------------------------------------
extern "C" void kernel_launch(void* const* d_in, const int* in_sizes, int n_in,
                              void* d_out, int out_size, void* d_ws, size_t ws_size,
                              hipStream_t stream) {
  const float* x = (const float*)d_in[0];
  const float* W = (const float*)d_in[1];
  float* out   = (float*)d_out;
  float* s     = (float*)d_ws;                       // 64K f32
  float* V     = s + 65536;                          // 64K f32 [b][n][d]
  float* sPart = V + 65536;                          // 2*128*32768 f32 = 32 MB
  float* part2 = sPart + 2ull * NIC * 32768;         // 16*32768 f32 = 2 MB

  const size_t need1 = (2ull * 65536 + 2ull * NIC * 32768) * 4;
  const size_t need2 = need1 + 16ull * 32768 * 4;
  const int usePart  = (ws_size >= need1) ? 1 : 0;
  const int useTwo   = (ws_size >= need2) ? 1 : 0;

  for (int r = 0; r < 3; ++r) {
    if (!usePart) caps_zero<<<256, 256, 0, stream>>>(s);
    caps_pass<<<256, 1024, 0, stream>>>(x, W, V, s, sPart, r, usePart);
    if (usePart) {
      if (useTwo) {
        caps_reduce1<<<512, 256, 0, stream>>>((const float4*)sPart, (float4*)part2);
        caps_reduce2<<<64, 256, 0, stream>>>((const float4*)part2, (float4*)s);
      } else {
        caps_reduceS<<<64, 256, 0, stream>>>((const float4*)sPart, (float4*)s);
      }
    }
    caps_squash<<<256, 256, 0, stream>>>(s, V, out, r == 2 ? 2 : (r == 0 ? 0 : 1));
  }
}